// Round 7
// baseline (266.213 us; speedup 1.0000x reference)
//
#include <hip/hip_runtime.h>

typedef unsigned short u16;
typedef unsigned int u32;
typedef __bf16 bf16x8 __attribute__((ext_vector_type(8)));
typedef float f32x4 __attribute__((ext_vector_type(4)));
typedef u16 u16x8 __attribute__((ext_vector_type(8)));
typedef u16 u16x4 __attribute__((ext_vector_type(4)));
typedef u32 u32x2 __attribute__((ext_vector_type(2)));

#define NH 16
#define DKK 64
#define SQ 2048
#define DD 1024

#define AS1 __attribute__((address_space(1)))
#define AS3 __attribute__((address_space(3)))

// softmax scale folded with log2(e): (1/8) * 1.44269504
#define QSCALE 0.1803368925f

__device__ inline u16 f2bf(float f) {
  union { float f; u32 u; } v; v.f = f;
  u32 u = v.u;
  u += 0x7FFFu + ((u >> 16) & 1u);
  return (u16)(u >> 16);
}

__device__ __forceinline__ u32 cvtpk(float lo, float hi) {
  u32 r;
  asm("v_cvt_pk_bf16_f32 %0, %1, %2" : "=v"(r) : "v"(lo), "v"(hi));
  return r;
}

__device__ inline u16x8 cvt8(const float* p) {
  float4 a = *(const float4*)p;
  float4 b = *(const float4*)(p + 4);
  u16x8 v;
  v[0] = f2bf(a.x); v[1] = f2bf(a.y); v[2] = f2bf(a.z); v[3] = f2bf(a.w);
  v[4] = f2bf(b.x); v[5] = f2bf(b.y); v[6] = f2bf(b.z); v[7] = f2bf(b.w);
  return v;
}

// direct global->LDS async copy, 16B/lane; LDS dest = wave-uniform base + lane*16
__device__ __forceinline__ void gload16(const u16* g, u16* l) {
  __builtin_amdgcn_global_load_lds((const AS1 u32*)(const void*)g,
                                   (AS3 u32*)(void*)l, 16, 0, 0);
}

// ---------------- f32 -> bf16 bulk convert: x (4M elems) then Wo (1M elems) ----------------
__global__ __launch_bounds__(256) void cvt_kernel(const float* __restrict__ x,
                                                  u16* __restrict__ xb,
                                                  const float* __restrict__ Wo,
                                                  u16* __restrict__ Wob) {
  int bid = blockIdx.x;
  const float* src; u16* dst; size_t base;
  if (bid < 2048) { src = x;  dst = xb;  base = (size_t)bid * 2048; }
  else            { src = Wo; dst = Wob; base = (size_t)(bid - 2048) * 2048; }
  size_t off = base + (size_t)threadIdx.x * 8;
  *(u16x8*)&dst[off] = cvt8(&src[off]);
}

// ---------------- Weight transpose: W(H,D,dk) f32 x3 -> WT bf16 [(t*1024 + h*64 + kk)][d] ----------------
__global__ __launch_bounds__(256) void wt_kernel(const float* __restrict__ Wq,
                                                 const float* __restrict__ Wk,
                                                 const float* __restrict__ Wv,
                                                 u16* __restrict__ WT) {
  __shared__ u16 sm[64][72];
  int bid = blockIdx.x;
  int t = bid >> 8;
  int rem = bid & 255;
  int h = rem >> 4;
  int d0 = (rem & 15) * 64;
  const float* src = (t == 0) ? Wq : (t == 1) ? Wk : Wv;
  int tid = threadIdx.x;
  for (int j = 0; j < 2; ++j) {
    int idx = tid + j * 256;
    int r = idx >> 3;
    int c0 = (idx & 7) * 8;
    *(u16x8*)&sm[r][c0] = cvt8(&src[(h * DD + d0 + r) * DKK + c0]);
  }
  __syncthreads();
  for (int j = 0; j < 2; ++j) {
    int idx = tid + j * 256;
    int r2 = idx >> 3;
    int c0 = (idx & 7) * 8;
    u16x8 vv;
    for (int i = 0; i < 8; ++i) vv[i] = sm[c0 + i][r2];
    int n = t * 1024 + h * 64 + r2;
    *(u16x8*)&WT[n * DD + d0 + c0] = vv;
  }
}

// ---------------- 128x128-tile bf16 GEMM (m97 structure): C = A[M,K] * B[N,K]^T ----------------
__global__ __launch_bounds__(256) void gemm128(const u16* __restrict__ A,
                                               const u16* __restrict__ Bm,
                                               int mode,
                                               u16* __restrict__ o0,
                                               u16* __restrict__ o1,
                                               u16* __restrict__ o2,
                                               float* __restrict__ of) {
  __shared__ u16 As[128 * 32];
  __shared__ u16 Bs[128 * 32];
  const int K = 1024;
  int m0 = blockIdx.x * 128;
  int n0 = blockIdx.y * 128;
  int tid = threadIdx.x;
  int w = tid >> 6, l = tid & 63;
  int lg = l >> 4, lr = l & 15;
  int wr = w >> 1, wc = w & 1;

  int srow = w * 32 + (l >> 2);
  int scol = (l & 3) * 8;
  const u16* gA = A + (size_t)(m0 + srow) * K + scol;
  const u16* gB = Bm + (size_t)(n0 + srow) * K + scol;
  u16* lA = As + w * 1024;
  u16* lB = Bs + w * 1024;

  f32x4 acc[4][4] = {};
  for (int kt = 0; kt < 32; ++kt) {
    int k0 = kt * 32;
    gload16(gA + k0, lA);
    gload16(gA + k0 + 16 * K, lA + 512);
    gload16(gB + k0, lB);
    gload16(gB + k0 + 16 * K, lB + 512);
    __syncthreads();
    bf16x8 a[4], b[4];
    #pragma unroll
    for (int m = 0; m < 4; ++m)
      a[m] = *(const bf16x8*)&As[(wr * 64 + m * 16 + lr) * 32 + lg * 8];
    #pragma unroll
    for (int n = 0; n < 4; ++n)
      b[n] = *(const bf16x8*)&Bs[(wc * 64 + n * 16 + lr) * 32 + lg * 8];
    #pragma unroll
    for (int m = 0; m < 4; ++m)
      #pragma unroll
      for (int n = 0; n < 4; ++n)
        acc[m][n] = __builtin_amdgcn_mfma_f32_16x16x32_bf16(a[m], b[n], acc[m][n], 0, 0, 0);
    __syncthreads();
  }

  if (mode == 1) {
    int mbase = m0 + wr * 64 + lg * 4;
    int nbase = n0 + wc * 64 + lr;
    #pragma unroll
    for (int m = 0; m < 4; ++m)
      #pragma unroll
      for (int n = 0; n < 4; ++n)
        #pragma unroll
        for (int rr = 0; rr < 4; ++rr)
          of[(size_t)(mbase + m * 16 + rr) * 1024 + nbase + n * 16] = acc[m][n][rr];
  } else {
    int t = n0 >> 10;
    int h = (((n0 & 1023) + wc * 64) >> 6);
    int bq = m0 >> 11;
    int sbase = (m0 & 2047) + wr * 64 + lg * 4;
    if (t < 2) {
      float sc = (t == 0) ? QSCALE : 1.0f;   // fold softmax scale*log2e into Q
      u16* o = (t == 0) ? o0 : o1;
      u16* op = o + (size_t)(bq * NH + h) * SQ * DKK;
      #pragma unroll
      for (int m = 0; m < 4; ++m)
        #pragma unroll
        for (int n = 0; n < 4; ++n)
          #pragma unroll
          for (int rr = 0; rr < 4; ++rr)
            op[(size_t)(sbase + m * 16 + rr) * DKK + n * 16 + lr] = f2bf(acc[m][n][rr] * sc);
    } else {
      u16* op = o2 + (size_t)(bq * NH + h) * DKK * SQ;
      #pragma unroll
      for (int m = 0; m < 4; ++m)
        #pragma unroll
        for (int n = 0; n < 4; ++n) {
          u16x4 vv;
          #pragma unroll
          for (int rr = 0; rr < 4; ++rr) vv[rr] = f2bf(acc[m][n][rr]);
          *(u16x4*)&op[(size_t)(n * 16 + lr) * SQ + sbase + m * 16] = vv;
        }
    }
  }
}

// ---------------- Flash attention v4 ----------------
// Unpaired strips (grid 32x32 = 1024 blocks, 4/CU); K double-buffered via gload_lds+swizzle
// (1 barrier/tile); V UNSTAGED (direct 16B global loads from Vt, issued first each tile);
// hoisted lane-const LDS addresses; defer-max; cvt_pk P pack; Q pre-scaled.
__global__ __launch_bounds__(256) void attn_kernel(const u16* __restrict__ Q,
                                                   const u16* __restrict__ Kg,
                                                   const u16* __restrict__ Vt,
                                                   u16* __restrict__ Cc) {
  __shared__ u16 Ks[2][64 * 64];
  __shared__ u16 Ps[4][16][72];    // per-wave P[q][kv]
  int s = blockIdx.x;              // strip: q rows s*64 .. s*64+63; s+1 kv tiles
  int bh = blockIdx.y;
  int tid = threadIdx.x;
  int w = tid >> 6, l = tid & 63;
  int lg = l >> 4, lr = l & 15;
  const u16* Qp = Q + (size_t)bh * SQ * DKK;
  const u16* Kp = Kg + (size_t)bh * SQ * DKK;
  const u16* Vp = Vt + (size_t)bh * DKK * SQ;
  int b = bh >> 4, h = bh & 15;
  int cur = 0;

  // K staging geometry (XOR-swizzled source granule, linear LDS dest)
  int lrow8 = l >> 3;              // 0..7
  int swz = (l & 7) ^ lrow8;
  int r7 = lr & 7;
  const u16* kSrc0 = Kp + (size_t)(w * 16 + lrow8) * DKK + swz * 8;
  const u16* kSrc1 = Kp + (size_t)(w * 16 + 8 + lrow8) * DKK + swz * 8;
  // hoisted lane-const K read offsets (elements); c adds compile-time 1024-elem steps
  int A0 = lr * 64 + (lg ^ r7) * 8;
  int A1 = lr * 64 + ((4 + lg) ^ r7) * 8;

  #define KSTAGE(buf, j0)                                                 \
    do {                                                                  \
      gload16(kSrc0 + (size_t)(j0) * DKK, &Ks[buf][(w * 16) * 64]);       \
      gload16(kSrc1 + (size_t)(j0) * DKK, &Ks[buf][(w * 16 + 8) * 64]);   \
    } while (0)

  // V per-lane row pointers: row dk = n*16+lr, col base lg*8 (advance 64/tile)
  const u16* vptr[4];
  #pragma unroll
  for (int n = 0; n < 4; ++n)
    vptr[n] = Vp + (size_t)(n * 16 + lr) * SQ + lg * 8;

  KSTAGE(0, 0);
  __syncthreads();

  int qrow = s * 64 + w * 16 + lr;
  bf16x8 qf0 = *(const bf16x8*)&Qp[(size_t)qrow * DKK + lg * 8];
  bf16x8 qf1 = *(const bf16x8*)&Qp[(size_t)qrow * DKK + 32 + lg * 8];
  f32x4 o[4] = {};
  float mrun = -1e30f, lrun = 0.f;

  for (int jt = 0; jt <= s; ++jt) {
    // V loads for THIS tile first (so their vmcnt wait doesn't drain next-K prefetch)
    bf16x8 vr0[4], vr1[4];
    #pragma unroll
    for (int n = 0; n < 4; ++n) {
      vr0[n] = *(const bf16x8*)(vptr[n]);
      vr1[n] = *(const bf16x8*)(vptr[n] + 32);
      vptr[n] += 64;
    }
    if (jt < s) KSTAGE(cur ^ 1, (jt + 1) * 64);

    const u16* kb = &Ks[cur][0];
    float p[16];
    #pragma unroll
    for (int c = 0; c < 4; ++c) {
      bf16x8 k0 = *(const bf16x8*)&kb[A0 + c * 1024];
      bf16x8 k1 = *(const bf16x8*)&kb[A1 + c * 1024];
      f32x4 z = {};
      z = __builtin_amdgcn_mfma_f32_16x16x32_bf16(k0, qf0, z, 0, 0, 0);
      z = __builtin_amdgcn_mfma_f32_16x16x32_bf16(k1, qf1, z, 0, 0, 0);
      #pragma unroll
      for (int rr = 0; rr < 4; ++rr) p[c * 4 + rr] = z[rr];
    }
    if (jt == s) {  // causal mask on diagonal tile
      int j0 = jt * 64;
      #pragma unroll
      for (int c = 0; c < 4; ++c)
        #pragma unroll
        for (int rr = 0; rr < 4; ++rr) {
          int kv = j0 + c * 16 + lg * 4 + rr;
          if (kv > qrow) p[c * 4 + rr] = -1e30f;
        }
    }
    float pm = p[0];
    #pragma unroll
    for (int i = 1; i < 16; ++i) pm = fmaxf(pm, p[i]);
    pm = fmaxf(pm, __shfl_xor(pm, 16, 64));
    pm = fmaxf(pm, __shfl_xor(pm, 32, 64));
    float alpha = 1.0f;
    if (__any(pm > mrun + 11.0f)) {          // defer-max
      float mnew = fmaxf(mrun, pm);
      alpha = exp2f(mrun - mnew);
      mrun = mnew;
      float af[4];
      #pragma unroll
      for (int rr = 0; rr < 4; ++rr) af[rr] = __shfl(alpha, ((l >> 4) << 2) + rr, 64);
      #pragma unroll
      for (int n = 0; n < 4; ++n)
        #pragma unroll
        for (int rr = 0; rr < 4; ++rr) o[n][rr] *= af[rr];
    }
    float su = 0.f;
    #pragma unroll
    for (int i = 0; i < 16; ++i) { p[i] = exp2f(p[i] - mrun); su += p[i]; }
    su += __shfl_xor(su, 16, 64);
    su += __shfl_xor(su, 32, 64);
    lrun = lrun * alpha + su;
    #pragma unroll
    for (int c = 0; c < 4; ++c) {
      u32x2 pk2;
      pk2[0] = cvtpk(p[c * 4 + 0], p[c * 4 + 1]);
      pk2[1] = cvtpk(p[c * 4 + 2], p[c * 4 + 3]);
      *(u32x2*)&Ps[w][lr][c * 16 + lg * 4] = pk2;
    }
    // PV: O[16q x 64d] += P[16 x 64] * V^T (V from registers)
    {
      bf16x8 pa0 = *(const bf16x8*)&Ps[w][lr][lg * 8];
      bf16x8 pa1 = *(const bf16x8*)&Ps[w][lr][32 + lg * 8];
      #pragma unroll
      for (int n = 0; n < 4; ++n)
        o[n] = __builtin_amdgcn_mfma_f32_16x16x32_bf16(pa0, vr0[n], o[n], 0, 0, 0);
      #pragma unroll
      for (int n = 0; n < 4; ++n)
        o[n] = __builtin_amdgcn_mfma_f32_16x16x32_bf16(pa1, vr1[n], o[n], 0, 0, 0);
    }
    __syncthreads();   // K dbuf handoff
    cur ^= 1;
  }

  float lrow[4];
  #pragma unroll
  for (int rr = 0; rr < 4; ++rr) lrow[rr] = __shfl(lrun, ((l >> 4) << 2) + rr, 64);
  int srow = s * 64 + w * 16 + lg * 4;
  #pragma unroll
  for (int n = 0; n < 4; ++n)
    #pragma unroll
    for (int rr = 0; rr < 4; ++rr) {
      float val = o[n][rr] / lrow[rr];
      Cc[((size_t)(b * SQ + srow + rr)) * DD + h * DKK + n * 16 + lr] = f2bf(val);
    }
  #undef KSTAGE
}

extern "C" void kernel_launch(void* const* d_in, const int* in_sizes, int n_in,
                              void* d_out, int out_size, void* d_ws, size_t ws_size,
                              hipStream_t stream) {
  (void)in_sizes; (void)n_in; (void)out_size; (void)ws_size;
  const float* x  = (const float*)d_in[0];
  const float* Wq = (const float*)d_in[1];
  const float* Wk = (const float*)d_in[2];
  const float* Wv = (const float*)d_in[3];
  const float* Wo = (const float*)d_in[4];
  float* out = (float*)d_out;
  u16* ws = (u16*)d_ws;
  u16* WT  = ws;                    // 3,145,728 elems
  u16* Qb  = WT + 3145728;          // 4,194,304
  u16* Kb  = Qb + 4194304;          // 4,194,304
  u16* Vb  = Kb + 4194304;          // 4,194,304 (B,H,dk,S)
  u16* XC  = Vb + 4194304;          // 4,194,304 — xb (bf16 x), later aliased as Cc
  u16* Wob = XC + 4194304;          // 1,048,576

  hipLaunchKernelGGL(cvt_kernel, dim3(2560), dim3(256), 0, stream, x, XC, Wo, Wob);
  hipLaunchKernelGGL(wt_kernel, dim3(768), dim3(256), 0, stream, Wq, Wk, Wv, WT);
  hipLaunchKernelGGL(gemm128, dim3(32, 24), dim3(256), 0, stream, XC, WT, 0, Qb, Kb, Vb, (float*)nullptr);
  hipLaunchKernelGGL(attn_kernel, dim3(32, 32), dim3(256), 0, stream, Qb, Kb, Vb, XC);
  hipLaunchKernelGGL(gemm128, dim3(32, 8), dim3(256), 0, stream, XC, Wob, 1, nullptr, nullptr, nullptr, out);
}

// Round 8
// 165.828 us; speedup vs baseline: 1.6054x; 1.6054x over previous
//
#include <hip/hip_runtime.h>

typedef unsigned short u16;
typedef unsigned int u32;
typedef __bf16 bf16x8 __attribute__((ext_vector_type(8)));
typedef float f32x4 __attribute__((ext_vector_type(4)));
typedef u16 u16x8 __attribute__((ext_vector_type(8)));
typedef u16 u16x4 __attribute__((ext_vector_type(4)));
typedef u32 u32x2 __attribute__((ext_vector_type(2)));

#define NH 16
#define DKK 64
#define SQ 2048
#define DD 1024

#define AS1 __attribute__((address_space(1)))
#define AS3 __attribute__((address_space(3)))

// softmax scale folded with log2(e): (1/8) * 1.44269504
#define QSCALE 0.1803368925f

__device__ inline u16 f2bf(float f) {
  union { float f; u32 u; } v; v.f = f;
  u32 u = v.u;
  u += 0x7FFFu + ((u >> 16) & 1u);
  return (u16)(u >> 16);
}

__device__ __forceinline__ u32 cvtpk(float lo, float hi) {
  u32 r;
  asm("v_cvt_pk_bf16_f32 %0, %1, %2" : "=v"(r) : "v"(lo), "v"(hi));
  return r;
}

__device__ inline u16x8 cvt8(const float* p) {
  float4 a = *(const float4*)p;
  float4 b = *(const float4*)(p + 4);
  u16x8 v;
  v[0] = f2bf(a.x); v[1] = f2bf(a.y); v[2] = f2bf(a.z); v[3] = f2bf(a.w);
  v[4] = f2bf(b.x); v[5] = f2bf(b.y); v[6] = f2bf(b.z); v[7] = f2bf(b.w);
  return v;
}

// direct global->LDS async copy, 16B/lane; LDS dest = wave-uniform base + lane*16
__device__ __forceinline__ void gload16(const u16* g, u16* l) {
  __builtin_amdgcn_global_load_lds((const AS1 u32*)(const void*)g,
                                   (AS3 u32*)(void*)l, 16, 0, 0);
}

// ---------------- f32 -> bf16 bulk convert: x (4M elems) then Wo (1M elems) ----------------
__global__ __launch_bounds__(256) void cvt_kernel(const float* __restrict__ x,
                                                  u16* __restrict__ xb,
                                                  const float* __restrict__ Wo,
                                                  u16* __restrict__ Wob) {
  int bid = blockIdx.x;
  const float* src; u16* dst; size_t base;
  if (bid < 2048) { src = x;  dst = xb;  base = (size_t)bid * 2048; }
  else            { src = Wo; dst = Wob; base = (size_t)(bid - 2048) * 2048; }
  size_t off = base + (size_t)threadIdx.x * 8;
  *(u16x8*)&dst[off] = cvt8(&src[off]);
}

// ---------------- Weight transpose: W(H,D,dk) f32 x3 -> WT bf16 [(t*1024 + h*64 + kk)][d] ----------------
__global__ __launch_bounds__(256) void wt_kernel(const float* __restrict__ Wq,
                                                 const float* __restrict__ Wk,
                                                 const float* __restrict__ Wv,
                                                 u16* __restrict__ WT) {
  __shared__ u16 sm[64][72];
  int bid = blockIdx.x;
  int t = bid >> 8;
  int rem = bid & 255;
  int h = rem >> 4;
  int d0 = (rem & 15) * 64;
  const float* src = (t == 0) ? Wq : (t == 1) ? Wk : Wv;
  int tid = threadIdx.x;
  for (int j = 0; j < 2; ++j) {
    int idx = tid + j * 256;
    int r = idx >> 3;
    int c0 = (idx & 7) * 8;
    *(u16x8*)&sm[r][c0] = cvt8(&src[(h * DD + d0 + r) * DKK + c0]);
  }
  __syncthreads();
  for (int j = 0; j < 2; ++j) {
    int idx = tid + j * 256;
    int r2 = idx >> 3;
    int c0 = (idx & 7) * 8;
    u16x8 vv;
    for (int i = 0; i < 8; ++i) vv[i] = sm[c0 + i][r2];
    int n = t * 1024 + h * 64 + r2;
    *(u16x8*)&WT[n * DD + d0 + c0] = vv;
  }
}

// ---------------- 128x128-tile bf16 GEMM (m97 structure): C = A[M,K] * B[N,K]^T ----------------
// mode 0: QKV epilogue (Q pre-scaled; Q,K via chunked LDS-transpose vector stores; V transposed direct)
// mode 1: f32 store to of[M,1024]
__global__ __launch_bounds__(256) void gemm128(const u16* __restrict__ A,
                                               const u16* __restrict__ Bm,
                                               int mode,
                                               u16* __restrict__ o0,
                                               u16* __restrict__ o1,
                                               u16* __restrict__ o2,
                                               float* __restrict__ of) {
  __shared__ u16 smem[2][128 * 32];   // As | Bs ; epilogue reuses both halves as one 16KB C-chunk
  u16* As = smem[0];
  u16* Bs = smem[1];
  const int K = 1024;
  int m0 = blockIdx.x * 128;
  int n0 = blockIdx.y * 128;
  int tid = threadIdx.x;
  int w = tid >> 6, l = tid & 63;
  int lg = l >> 4, lr = l & 15;
  int wr = w >> 1, wc = w & 1;

  int srow = w * 32 + (l >> 2);
  int scol = (l & 3) * 8;
  const u16* gA = A + (size_t)(m0 + srow) * K + scol;
  const u16* gB = Bm + (size_t)(n0 + srow) * K + scol;
  u16* lA = As + w * 1024;
  u16* lB = Bs + w * 1024;

  f32x4 acc[4][4] = {};
  for (int kt = 0; kt < 32; ++kt) {
    int k0 = kt * 32;
    gload16(gA + k0, lA);
    gload16(gA + k0 + 16 * K, lA + 512);
    gload16(gB + k0, lB);
    gload16(gB + k0 + 16 * K, lB + 512);
    __syncthreads();
    bf16x8 a[4], b[4];
    #pragma unroll
    for (int m = 0; m < 4; ++m)
      a[m] = *(const bf16x8*)&As[(wr * 64 + m * 16 + lr) * 32 + lg * 8];
    #pragma unroll
    for (int n = 0; n < 4; ++n)
      b[n] = *(const bf16x8*)&Bs[(wc * 64 + n * 16 + lr) * 32 + lg * 8];
    #pragma unroll
    for (int m = 0; m < 4; ++m)
      #pragma unroll
      for (int n = 0; n < 4; ++n)
        acc[m][n] = __builtin_amdgcn_mfma_f32_16x16x32_bf16(a[m], b[n], acc[m][n], 0, 0, 0);
    __syncthreads();
  }

  if (mode == 1) {
    int mbase = m0 + wr * 64 + lg * 4;
    int nbase = n0 + wc * 64 + lr;
    #pragma unroll
    for (int m = 0; m < 4; ++m)
      #pragma unroll
      for (int n = 0; n < 4; ++n)
        #pragma unroll
        for (int rr = 0; rr < 4; ++rr)
          of[(size_t)(mbase + m * 16 + rr) * 1024 + nbase + n * 16] = acc[m][n][rr];
  } else {
    int t = n0 >> 10;                       // uniform per block
    int bq = m0 >> 11;
    int sbase = (m0 & 2047);
    if (t < 2) {
      // Q/K: chunked LDS transpose -> coalesced u16x8 stores
      float sc = (t == 0) ? QSCALE : 1.0f;
      u16* o = (t == 0) ? o0 : o1;
      char* ct = (char*)smem;
      #pragma unroll
      for (int ch = 0; ch < 2; ++ch) {
        if (wc == ch) {
          #pragma unroll
          for (int m = 0; m < 4; ++m)
            #pragma unroll
            for (int rr = 0; rr < 4; ++rr) {
              int row = wr * 64 + m * 16 + lg * 4 + rr;
              int swz = (row & 7) << 4;
              #pragma unroll
              for (int n = 0; n < 4; ++n)
                *(u16*)(ct + row * 128 + (((n * 16 + lr) * 2) ^ swz)) =
                    f2bf(acc[m][n][rr] * sc);
            }
        }
        __syncthreads();
        {
          int r = tid >> 1;
          int cb = (tid & 1) * 64;           // byte col base within 128B row
          int h2 = ((n0 & 1023) + ch * 64) >> 6;
          int rswz = (r & 7) << 4;
          u16* op = o + (size_t)(bq * NH + h2) * SQ * DKK
                      + (size_t)(sbase + r) * DKK + (tid & 1) * 32;
          #pragma unroll
          for (int i = 0; i < 4; ++i)
            *(u16x8*)(op + i * 8) =
                *(const u16x8*)(ct + r * 128 + ((cb + i * 16) ^ rswz));
        }
        __syncthreads();
      }
    } else {
      int h = (((n0 & 1023) + wc * 64) >> 6);
      int sb2 = sbase + wr * 64 + lg * 4;
      u16* op = o2 + (size_t)(bq * NH + h) * DKK * SQ;
      #pragma unroll
      for (int m = 0; m < 4; ++m)
        #pragma unroll
        for (int n = 0; n < 4; ++n) {
          u16x4 vv;
          #pragma unroll
          for (int rr = 0; rr < 4; ++rr) vv[rr] = f2bf(acc[m][n][rr]);
          *(u16x4*)&op[(size_t)(n * 16 + lr) * SQ + sb2 + m * 16] = vv;
        }
    }
  }
}

// ---------------- Flash attention v5 ----------------
// Round-6 core (K+V gload_lds staged, swizzled, dbuf, 1 barrier/tile) with:
// unpaired strips via balance permutation (every CU's 4 resident blocks sum to 66 tiles),
// 40KB LDS (Ps de-padded + XOR swizzle) -> 4 blocks/CU, setprio around MFMA.
__global__ __launch_bounds__(256) void attn_kernel(const u16* __restrict__ Q,
                                                   const u16* __restrict__ Kg,
                                                   const u16* __restrict__ Vt,
                                                   u16* __restrict__ Cc) {
  __shared__ u16 Ks[2][64 * 64];
  __shared__ u16 Vs[2][64 * 64];   // [dk][kv]
  __shared__ u16 Ps[4 * 16 * 64];  // per-wave P[q][kv], XOR-swizzled rows
  int bh = blockIdx.x;             // bh fastest -> round-robin spreads strips
  int y = blockIdx.y;
  int a = y & 7, bsel = y >> 3;
  int s = (bsel == 0) ? 2 * a : (bsel == 1) ? 2 * a + 1
        : (bsel == 2) ? 30 - 2 * a : 31 - 2 * a;   // per-CU sums = 66 tiles
  int tid = threadIdx.x;
  int w = tid >> 6, l = tid & 63;
  int lg = l >> 4, lr = l & 15;
  const u16* Qp = Q + (size_t)bh * SQ * DKK;
  const u16* Kp = Kg + (size_t)bh * SQ * DKK;
  const u16* Vp = Vt + (size_t)bh * DKK * SQ;
  int b = bh >> 4, h = bh & 15;
  int cur = 0;

  // staging geometry (XOR-swizzled source granule, linear LDS dest)
  int lrow8 = l >> 3;
  int swz = (l & 7) ^ lrow8;
  int r7 = lr & 7;
  const u16* kSrc0 = Kp + (size_t)(w * 16 + lrow8) * DKK + swz * 8;
  const u16* kSrc1 = Kp + (size_t)(w * 16 + 8 + lrow8) * DKK + swz * 8;
  const u16* vSrc0 = Vp + (size_t)(w * 16 + lrow8) * SQ + swz * 8;
  const u16* vSrc1 = Vp + (size_t)(w * 16 + 8 + lrow8) * SQ + swz * 8;

  #define STAGE(buf, j0)                                                  \
    do {                                                                  \
      gload16(kSrc0 + (size_t)(j0) * DKK, &Ks[buf][(w * 16) * 64]);       \
      gload16(kSrc1 + (size_t)(j0) * DKK, &Ks[buf][(w * 16 + 8) * 64]);   \
      gload16(vSrc0 + (j0), &Vs[buf][(w * 16) * 64]);                     \
      gload16(vSrc1 + (j0), &Vs[buf][(w * 16 + 8) * 64]);                 \
    } while (0)

  STAGE(0, 0);
  __syncthreads();

  int qrow = s * 64 + w * 16 + lr;
  bf16x8 qf0 = *(const bf16x8*)&Qp[(size_t)qrow * DKK + lg * 8];
  bf16x8 qf1 = *(const bf16x8*)&Qp[(size_t)qrow * DKK + 32 + lg * 8];
  f32x4 o[4] = {};
  float mrun = -1e30f, lrun = 0.f;
  int swzP = r7 << 4;
  char* PsB = (char*)Ps + w * 2048 + lr * 128;

  for (int jt = 0; jt <= s; ++jt) {
    if (jt < s) STAGE(cur ^ 1, (jt + 1) * 64);

    float p[16];
    __builtin_amdgcn_s_setprio(1);
    #pragma unroll
    for (int c = 0; c < 4; ++c) {
      int R = c * 16 + lr;
      const u16* kr = &Ks[cur][R * 64];
      bf16x8 k0 = *(const bf16x8*)&kr[(lg ^ r7) * 8];
      bf16x8 k1 = *(const bf16x8*)&kr[((4 + lg) ^ r7) * 8];
      f32x4 z = {};
      z = __builtin_amdgcn_mfma_f32_16x16x32_bf16(k0, qf0, z, 0, 0, 0);
      z = __builtin_amdgcn_mfma_f32_16x16x32_bf16(k1, qf1, z, 0, 0, 0);
      #pragma unroll
      for (int rr = 0; rr < 4; ++rr) p[c * 4 + rr] = z[rr];
    }
    __builtin_amdgcn_s_setprio(0);
    if (jt == s) {  // causal mask on diagonal tile
      int j0 = jt * 64;
      #pragma unroll
      for (int c = 0; c < 4; ++c)
        #pragma unroll
        for (int rr = 0; rr < 4; ++rr) {
          int kv = j0 + c * 16 + lg * 4 + rr;
          if (kv > qrow) p[c * 4 + rr] = -1e30f;
        }
    }
    // max via balanced triple tree (v_max3)
    float t0 = fmaxf(fmaxf(p[0], p[1]), p[2]);
    float t1 = fmaxf(fmaxf(p[3], p[4]), p[5]);
    float t2 = fmaxf(fmaxf(p[6], p[7]), p[8]);
    float t3 = fmaxf(fmaxf(p[9], p[10]), p[11]);
    float t4 = fmaxf(fmaxf(p[12], p[13]), p[14]);
    float pm = fmaxf(fmaxf(fmaxf(t0, t1), fmaxf(t2, t3)), fmaxf(t4, p[15]));
    pm = fmaxf(pm, __shfl_xor(pm, 16, 64));
    pm = fmaxf(pm, __shfl_xor(pm, 32, 64));
    float alpha = 1.0f;
    if (__any(pm > mrun + 11.0f)) {          // defer-max
      float mnew = fmaxf(mrun, pm);
      alpha = exp2f(mrun - mnew);
      mrun = mnew;
      float af[4];
      #pragma unroll
      for (int rr = 0; rr < 4; ++rr) af[rr] = __shfl(alpha, ((l >> 4) << 2) + rr, 64);
      #pragma unroll
      for (int n = 0; n < 4; ++n)
        #pragma unroll
        for (int rr = 0; rr < 4; ++rr) o[n][rr] *= af[rr];
    }
    float su = 0.f;
    #pragma unroll
    for (int i = 0; i < 16; ++i) { p[i] = exp2f(p[i] - mrun); su += p[i]; }
    su += __shfl_xor(su, 16, 64);
    su += __shfl_xor(su, 32, 64);
    lrun = lrun * alpha + su;
    #pragma unroll
    for (int c = 0; c < 4; ++c) {
      u32x2 pk2;
      pk2[0] = cvtpk(p[c * 4 + 0], p[c * 4 + 1]);
      pk2[1] = cvtpk(p[c * 4 + 2], p[c * 4 + 3]);
      *(u32x2*)(PsB + ((c * 32 + lg * 8) ^ swzP)) = pk2;
    }
    // PV: O[16q x 64d] += P[16 x 64] * V^T
    {
      bf16x8 pa0 = *(const bf16x8*)(PsB + ((lg * 16) ^ swzP));
      bf16x8 pa1 = *(const bf16x8*)(PsB + ((64 + lg * 16) ^ swzP));
      __builtin_amdgcn_s_setprio(1);
      #pragma unroll
      for (int n = 0; n < 4; ++n) {
        int R2 = n * 16 + lr;
        bf16x8 vb0 = *(const bf16x8*)&Vs[cur][R2 * 64 + ((lg ^ r7) * 8)];
        o[n] = __builtin_amdgcn_mfma_f32_16x16x32_bf16(pa0, vb0, o[n], 0, 0, 0);
        bf16x8 vb1 = *(const bf16x8*)&Vs[cur][R2 * 64 + (((4 + lg) ^ r7) * 8)];
        o[n] = __builtin_amdgcn_mfma_f32_16x16x32_bf16(pa1, vb1, o[n], 0, 0, 0);
      }
      __builtin_amdgcn_s_setprio(0);
    }
    __syncthreads();   // dbuf handoff (drains prefetch)
    cur ^= 1;
  }

  float lrow[4];
  #pragma unroll
  for (int rr = 0; rr < 4; ++rr) lrow[rr] = __shfl(lrun, ((l >> 4) << 2) + rr, 64);
  int srow = s * 64 + w * 16 + lg * 4;
  #pragma unroll
  for (int n = 0; n < 4; ++n)
    #pragma unroll
    for (int rr = 0; rr < 4; ++rr) {
      float val = o[n][rr] / lrow[rr];
      Cc[((size_t)(b * SQ + srow + rr)) * DD + h * DKK + n * 16 + lr] = f2bf(val);
    }
  #undef STAGE
}

extern "C" void kernel_launch(void* const* d_in, const int* in_sizes, int n_in,
                              void* d_out, int out_size, void* d_ws, size_t ws_size,
                              hipStream_t stream) {
  (void)in_sizes; (void)n_in; (void)out_size; (void)ws_size;
  const float* x  = (const float*)d_in[0];
  const float* Wq = (const float*)d_in[1];
  const float* Wk = (const float*)d_in[2];
  const float* Wv = (const float*)d_in[3];
  const float* Wo = (const float*)d_in[4];
  float* out = (float*)d_out;
  u16* ws = (u16*)d_ws;
  u16* WT  = ws;                    // 3,145,728 elems
  u16* Qb  = WT + 3145728;          // 4,194,304
  u16* Kb  = Qb + 4194304;          // 4,194,304
  u16* Vb  = Kb + 4194304;          // 4,194,304 (B,H,dk,S)
  u16* XC  = Vb + 4194304;          // 4,194,304 — xb (bf16 x), later aliased as Cc
  u16* Wob = XC + 4194304;          // 1,048,576

  hipLaunchKernelGGL(cvt_kernel, dim3(2560), dim3(256), 0, stream, x, XC, Wo, Wob);
  hipLaunchKernelGGL(wt_kernel, dim3(768), dim3(256), 0, stream, Wq, Wk, Wv, WT);
  hipLaunchKernelGGL(gemm128, dim3(32, 24), dim3(256), 0, stream, XC, WT, 0, Qb, Kb, Vb, (float*)nullptr);
  hipLaunchKernelGGL(attn_kernel, dim3(32, 32), dim3(256), 0, stream, Qb, Kb, Vb, XC);
  hipLaunchKernelGGL(gemm128, dim3(32, 8), dim3(256), 0, stream, XC, Wob, 1, nullptr, nullptr, nullptr, out);
}

// Round 9
// 140.568 us; speedup vs baseline: 1.8938x; 1.1797x over previous
//
#include <hip/hip_runtime.h>

typedef unsigned short u16;
typedef unsigned int u32;
typedef __bf16 bf16x8 __attribute__((ext_vector_type(8)));
typedef float f32x4 __attribute__((ext_vector_type(4)));
typedef u16 u16x8 __attribute__((ext_vector_type(8)));
typedef u16 u16x4 __attribute__((ext_vector_type(4)));
typedef u32 u32x2 __attribute__((ext_vector_type(2)));

#define NH 16
#define DKK 64
#define SQ 2048
#define DD 1024

#define AS1 __attribute__((address_space(1)))
#define AS3 __attribute__((address_space(3)))

// softmax scale folded with log2(e): (1/8) * 1.44269504
#define QSCALE 0.1803368925f

__device__ inline u16 f2bf(float f) {
  union { float f; u32 u; } v; v.f = f;
  u32 u = v.u;
  u += 0x7FFFu + ((u >> 16) & 1u);
  return (u16)(u >> 16);
}

__device__ __forceinline__ u32 cvtpk(float lo, float hi) {
  u32 r;
  asm("v_cvt_pk_bf16_f32 %0, %1, %2" : "=v"(r) : "v"(lo), "v"(hi));
  return r;
}

__device__ inline u16x8 cvt8(const float* p) {
  float4 a = *(const float4*)p;
  float4 b = *(const float4*)(p + 4);
  u16x8 v;
  v[0] = f2bf(a.x); v[1] = f2bf(a.y); v[2] = f2bf(a.z); v[3] = f2bf(a.w);
  v[4] = f2bf(b.x); v[5] = f2bf(b.y); v[6] = f2bf(b.z); v[7] = f2bf(b.w);
  return v;
}

// direct global->LDS async copy, 16B/lane; LDS dest = wave-uniform base + lane*16
__device__ __forceinline__ void gload16(const u16* g, u16* l) {
  __builtin_amdgcn_global_load_lds((const AS1 u32*)(const void*)g,
                                   (AS3 u32*)(void*)l, 16, 0, 0);
}

// ---------------- f32 -> bf16 bulk convert: x (4M elems) then Wo (1M elems) ----------------
__global__ __launch_bounds__(256) void cvt_kernel(const float* __restrict__ x,
                                                  u16* __restrict__ xb,
                                                  const float* __restrict__ Wo,
                                                  u16* __restrict__ Wob) {
  int bid = blockIdx.x;
  const float* src; u16* dst; size_t base;
  if (bid < 2048) { src = x;  dst = xb;  base = (size_t)bid * 2048; }
  else            { src = Wo; dst = Wob; base = (size_t)(bid - 2048) * 2048; }
  size_t off = base + (size_t)threadIdx.x * 8;
  *(u16x8*)&dst[off] = cvt8(&src[off]);
}

// ---------------- Weight transpose: W(H,D,dk) f32 x3 -> WT bf16 [(t*1024 + h*64 + kk)][d] ----------------
__global__ __launch_bounds__(256) void wt_kernel(const float* __restrict__ Wq,
                                                 const float* __restrict__ Wk,
                                                 const float* __restrict__ Wv,
                                                 u16* __restrict__ WT) {
  __shared__ u16 sm[64][72];
  int bid = blockIdx.x;
  int t = bid >> 8;
  int rem = bid & 255;
  int h = rem >> 4;
  int d0 = (rem & 15) * 64;
  const float* src = (t == 0) ? Wq : (t == 1) ? Wk : Wv;
  int tid = threadIdx.x;
  for (int j = 0; j < 2; ++j) {
    int idx = tid + j * 256;
    int r = idx >> 3;
    int c0 = (idx & 7) * 8;
    *(u16x8*)&sm[r][c0] = cvt8(&src[(h * DD + d0 + r) * DKK + c0]);
  }
  __syncthreads();
  for (int j = 0; j < 2; ++j) {
    int idx = tid + j * 256;
    int r2 = idx >> 3;
    int c0 = (idx & 7) * 8;
    u16x8 vv;
    for (int i = 0; i < 8; ++i) vv[i] = sm[c0 + i][r2];
    int n = t * 1024 + h * 64 + r2;
    *(u16x8*)&WT[n * DD + d0 + c0] = vv;
  }
}

// ---------------- 128x128-tile bf16 GEMM (m97 structure + LDS granule swizzle) ----------------
// LDS[row][g] holds global granule (g ^ ((row>>1)&3)); read with lg^((lr>>1)&3).
// mode 0: QKV epilogue (direct stores, round-6 proven); mode 1: f32 store.
__global__ __launch_bounds__(256) void gemm128(const u16* __restrict__ A,
                                               const u16* __restrict__ Bm,
                                               int mode,
                                               u16* __restrict__ o0,
                                               u16* __restrict__ o1,
                                               u16* __restrict__ o2,
                                               float* __restrict__ of) {
  __shared__ u16 As[128 * 32];
  __shared__ u16 Bs[128 * 32];
  const int K = 1024;
  int m0 = blockIdx.x * 128;
  int n0 = blockIdx.y * 128;
  int tid = threadIdx.x;
  int w = tid >> 6, l = tid & 63;
  int lg = l >> 4, lr = l & 15;
  int wr = w >> 1, wc = w & 1;

  int srow = w * 32 + (l >> 2);
  int sg = (l & 3) ^ ((l >> 3) & 3);        // pre-swizzled source granule
  const u16* gA = A + (size_t)(m0 + srow) * K + sg * 8;
  const u16* gB = Bm + (size_t)(n0 + srow) * K + sg * 8;
  u16* lA = As + w * 1024;
  u16* lB = Bs + w * 1024;
  int gsw = (lr >> 1) & 3;                  // read-side swizzle key

  f32x4 acc[4][4] = {};
  for (int kt = 0; kt < 32; ++kt) {
    int k0 = kt * 32;
    gload16(gA + k0, lA);
    gload16(gA + k0 + 16 * K, lA + 512);
    gload16(gB + k0, lB);
    gload16(gB + k0 + 16 * K, lB + 512);
    __syncthreads();
    bf16x8 a[4], b[4];
    #pragma unroll
    for (int m = 0; m < 4; ++m)
      a[m] = *(const bf16x8*)&As[(wr * 64 + m * 16 + lr) * 32 + ((lg ^ gsw) * 8)];
    #pragma unroll
    for (int n = 0; n < 4; ++n)
      b[n] = *(const bf16x8*)&Bs[(wc * 64 + n * 16 + lr) * 32 + ((lg ^ gsw) * 8)];
    #pragma unroll
    for (int m = 0; m < 4; ++m)
      #pragma unroll
      for (int n = 0; n < 4; ++n)
        acc[m][n] = __builtin_amdgcn_mfma_f32_16x16x32_bf16(a[m], b[n], acc[m][n], 0, 0, 0);
    __syncthreads();
  }

  if (mode == 1) {
    int mbase = m0 + wr * 64 + lg * 4;
    int nbase = n0 + wc * 64 + lr;
    #pragma unroll
    for (int m = 0; m < 4; ++m)
      #pragma unroll
      for (int n = 0; n < 4; ++n)
        #pragma unroll
        for (int rr = 0; rr < 4; ++rr)
          of[(size_t)(mbase + m * 16 + rr) * 1024 + nbase + n * 16] = acc[m][n][rr];
  } else {
    int t = n0 >> 10;
    int h = (((n0 & 1023) + wc * 64) >> 6);
    int bq = m0 >> 11;
    int sbase = (m0 & 2047) + wr * 64 + lg * 4;
    if (t < 2) {
      float sc = (t == 0) ? QSCALE : 1.0f;   // fold softmax scale*log2e into Q
      u16* o = (t == 0) ? o0 : o1;
      u16* op = o + (size_t)(bq * NH + h) * SQ * DKK;
      #pragma unroll
      for (int m = 0; m < 4; ++m)
        #pragma unroll
        for (int n = 0; n < 4; ++n)
          #pragma unroll
          for (int rr = 0; rr < 4; ++rr)
            op[(size_t)(sbase + m * 16 + rr) * DKK + n * 16 + lr] = f2bf(acc[m][n][rr] * sc);
    } else {
      u16* op = o2 + (size_t)(bq * NH + h) * DKK * SQ;
      #pragma unroll
      for (int m = 0; m < 4; ++m)
        #pragma unroll
        for (int n = 0; n < 4; ++n) {
          u16x4 vv;
          #pragma unroll
          for (int rr = 0; rr < 4; ++rr) vv[rr] = f2bf(acc[m][n][rr]);
          *(u16x4*)&op[(size_t)(n * 16 + lr) * SQ + sbase + m * 16] = vv;
        }
    }
  }
}

// ---------------- Flash attention v5 (round-8 version, kept) ----------------
__global__ __launch_bounds__(256) void attn_kernel(const u16* __restrict__ Q,
                                                   const u16* __restrict__ Kg,
                                                   const u16* __restrict__ Vt,
                                                   u16* __restrict__ Cc) {
  __shared__ u16 Ks[2][64 * 64];
  __shared__ u16 Vs[2][64 * 64];   // [dk][kv]
  __shared__ u16 Ps[4 * 16 * 64];  // per-wave P[q][kv], XOR-swizzled rows
  int bh = blockIdx.x;             // bh fastest -> round-robin spreads strips
  int y = blockIdx.y;
  int a = y & 7, bsel = y >> 3;
  int s = (bsel == 0) ? 2 * a : (bsel == 1) ? 2 * a + 1
        : (bsel == 2) ? 30 - 2 * a : 31 - 2 * a;   // per-CU sums = 66 tiles
  int tid = threadIdx.x;
  int w = tid >> 6, l = tid & 63;
  int lg = l >> 4, lr = l & 15;
  const u16* Qp = Q + (size_t)bh * SQ * DKK;
  const u16* Kp = Kg + (size_t)bh * SQ * DKK;
  const u16* Vp = Vt + (size_t)bh * DKK * SQ;
  int b = bh >> 4, h = bh & 15;
  int cur = 0;

  int lrow8 = l >> 3;
  int swz = (l & 7) ^ lrow8;
  int r7 = lr & 7;
  const u16* kSrc0 = Kp + (size_t)(w * 16 + lrow8) * DKK + swz * 8;
  const u16* kSrc1 = Kp + (size_t)(w * 16 + 8 + lrow8) * DKK + swz * 8;
  const u16* vSrc0 = Vp + (size_t)(w * 16 + lrow8) * SQ + swz * 8;
  const u16* vSrc1 = Vp + (size_t)(w * 16 + 8 + lrow8) * SQ + swz * 8;

  #define STAGE(buf, j0)                                                  \
    do {                                                                  \
      gload16(kSrc0 + (size_t)(j0) * DKK, &Ks[buf][(w * 16) * 64]);       \
      gload16(kSrc1 + (size_t)(j0) * DKK, &Ks[buf][(w * 16 + 8) * 64]);   \
      gload16(vSrc0 + (j0), &Vs[buf][(w * 16) * 64]);                     \
      gload16(vSrc1 + (j0), &Vs[buf][(w * 16 + 8) * 64]);                 \
    } while (0)

  STAGE(0, 0);
  __syncthreads();

  int qrow = s * 64 + w * 16 + lr;
  bf16x8 qf0 = *(const bf16x8*)&Qp[(size_t)qrow * DKK + lg * 8];
  bf16x8 qf1 = *(const bf16x8*)&Qp[(size_t)qrow * DKK + 32 + lg * 8];
  f32x4 o[4] = {};
  float mrun = -1e30f, lrun = 0.f;
  int swzP = r7 << 4;
  char* PsB = (char*)Ps + w * 2048 + lr * 128;

  for (int jt = 0; jt <= s; ++jt) {
    if (jt < s) STAGE(cur ^ 1, (jt + 1) * 64);

    float p[16];
    __builtin_amdgcn_s_setprio(1);
    #pragma unroll
    for (int c = 0; c < 4; ++c) {
      int R = c * 16 + lr;
      const u16* kr = &Ks[cur][R * 64];
      bf16x8 k0 = *(const bf16x8*)&kr[(lg ^ r7) * 8];
      bf16x8 k1 = *(const bf16x8*)&kr[((4 + lg) ^ r7) * 8];
      f32x4 z = {};
      z = __builtin_amdgcn_mfma_f32_16x16x32_bf16(k0, qf0, z, 0, 0, 0);
      z = __builtin_amdgcn_mfma_f32_16x16x32_bf16(k1, qf1, z, 0, 0, 0);
      #pragma unroll
      for (int rr = 0; rr < 4; ++rr) p[c * 4 + rr] = z[rr];
    }
    __builtin_amdgcn_s_setprio(0);
    if (jt == s) {  // causal mask on diagonal tile
      int j0 = jt * 64;
      #pragma unroll
      for (int c = 0; c < 4; ++c)
        #pragma unroll
        for (int rr = 0; rr < 4; ++rr) {
          int kv = j0 + c * 16 + lg * 4 + rr;
          if (kv > qrow) p[c * 4 + rr] = -1e30f;
        }
    }
    float t0 = fmaxf(fmaxf(p[0], p[1]), p[2]);
    float t1 = fmaxf(fmaxf(p[3], p[4]), p[5]);
    float t2 = fmaxf(fmaxf(p[6], p[7]), p[8]);
    float t3 = fmaxf(fmaxf(p[9], p[10]), p[11]);
    float t4 = fmaxf(fmaxf(p[12], p[13]), p[14]);
    float pm = fmaxf(fmaxf(fmaxf(t0, t1), fmaxf(t2, t3)), fmaxf(t4, p[15]));
    pm = fmaxf(pm, __shfl_xor(pm, 16, 64));
    pm = fmaxf(pm, __shfl_xor(pm, 32, 64));
    float alpha = 1.0f;
    if (__any(pm > mrun + 11.0f)) {          // defer-max
      float mnew = fmaxf(mrun, pm);
      alpha = exp2f(mrun - mnew);
      mrun = mnew;
      float af[4];
      #pragma unroll
      for (int rr = 0; rr < 4; ++rr) af[rr] = __shfl(alpha, ((l >> 4) << 2) + rr, 64);
      #pragma unroll
      for (int n = 0; n < 4; ++n)
        #pragma unroll
        for (int rr = 0; rr < 4; ++rr) o[n][rr] *= af[rr];
    }
    float su = 0.f;
    #pragma unroll
    for (int i = 0; i < 16; ++i) { p[i] = exp2f(p[i] - mrun); su += p[i]; }
    su += __shfl_xor(su, 16, 64);
    su += __shfl_xor(su, 32, 64);
    lrun = lrun * alpha + su;
    #pragma unroll
    for (int c = 0; c < 4; ++c) {
      u32x2 pk2;
      pk2[0] = cvtpk(p[c * 4 + 0], p[c * 4 + 1]);
      pk2[1] = cvtpk(p[c * 4 + 2], p[c * 4 + 3]);
      *(u32x2*)(PsB + ((c * 32 + lg * 8) ^ swzP)) = pk2;
    }
    {
      bf16x8 pa0 = *(const bf16x8*)(PsB + ((lg * 16) ^ swzP));
      bf16x8 pa1 = *(const bf16x8*)(PsB + ((64 + lg * 16) ^ swzP));
      __builtin_amdgcn_s_setprio(1);
      #pragma unroll
      for (int n = 0; n < 4; ++n) {
        int R2 = n * 16 + lr;
        bf16x8 vb0 = *(const bf16x8*)&Vs[cur][R2 * 64 + ((lg ^ r7) * 8)];
        o[n] = __builtin_amdgcn_mfma_f32_16x16x32_bf16(pa0, vb0, o[n], 0, 0, 0);
        bf16x8 vb1 = *(const bf16x8*)&Vs[cur][R2 * 64 + (((4 + lg) ^ r7) * 8)];
        o[n] = __builtin_amdgcn_mfma_f32_16x16x32_bf16(pa1, vb1, o[n], 0, 0, 0);
      }
      __builtin_amdgcn_s_setprio(0);
    }
    __syncthreads();   // dbuf handoff (drains prefetch)
    cur ^= 1;
  }

  float lrow[4];
  #pragma unroll
  for (int rr = 0; rr < 4; ++rr) lrow[rr] = __shfl(lrun, ((l >> 4) << 2) + rr, 64);
  int srow = s * 64 + w * 16 + lg * 4;
  #pragma unroll
  for (int n = 0; n < 4; ++n)
    #pragma unroll
    for (int rr = 0; rr < 4; ++rr) {
      float val = o[n][rr] / lrow[rr];
      Cc[((size_t)(b * SQ + srow + rr)) * DD + h * DKK + n * 16 + lr] = f2bf(val);
    }
  #undef STAGE
}

extern "C" void kernel_launch(void* const* d_in, const int* in_sizes, int n_in,
                              void* d_out, int out_size, void* d_ws, size_t ws_size,
                              hipStream_t stream) {
  (void)in_sizes; (void)n_in; (void)out_size; (void)ws_size;
  const float* x  = (const float*)d_in[0];
  const float* Wq = (const float*)d_in[1];
  const float* Wk = (const float*)d_in[2];
  const float* Wv = (const float*)d_in[3];
  const float* Wo = (const float*)d_in[4];
  float* out = (float*)d_out;
  u16* ws = (u16*)d_ws;
  u16* WT  = ws;                    // 3,145,728 elems
  u16* Qb  = WT + 3145728;          // 4,194,304
  u16* Kb  = Qb + 4194304;          // 4,194,304
  u16* Vb  = Kb + 4194304;          // 4,194,304 (B,H,dk,S)
  u16* XC  = Vb + 4194304;          // 4,194,304 — xb (bf16 x), later aliased as Cc
  u16* Wob = XC + 4194304;          // 1,048,576

  hipLaunchKernelGGL(cvt_kernel, dim3(2560), dim3(256), 0, stream, x, XC, Wo, Wob);
  hipLaunchKernelGGL(wt_kernel, dim3(768), dim3(256), 0, stream, Wq, Wk, Wv, WT);
  hipLaunchKernelGGL(gemm128, dim3(32, 24), dim3(256), 0, stream, XC, WT, 0, Qb, Kb, Vb, (float*)nullptr);
  hipLaunchKernelGGL(attn_kernel, dim3(32, 32), dim3(256), 0, stream, Qb, Kb, Vb, XC);
  hipLaunchKernelGGL(gemm128, dim3(32, 8), dim3(256), 0, stream, XC, Wob, 1, nullptr, nullptr, nullptr, out);
}